// Round 3
// baseline (636.962 us; speedup 1.0000x reference)
//
#include <hip/hip_runtime.h>
#include <hip/hip_bf16.h>
#include <math.h>

// Problem constants
#define D_DIM 128
#define M_CODES 2048
#define BN_TOT 65536           // B*N = 16*4096
#define OUT_LOSS 8388608       // flat offset of loss
#define OUT_PERP 8388609       // flat offset of perp
#define OUT_IDX 8388610        // flat offset of indices
#define MARGIN 2e-3f           // covers ref fp32 noise (~1.6e-5) with 100x margin

// ws byte offsets
#define WS_WT 0                // float wT[128][2048]          (1 MB)
#define WS_L2K 1048576         // float l2k[2048]              (8 KB)
#define WS_IDX 1056768         // int best_idx[65536]          (256 KB)
#define WS_PART 1318912        // float loss_part[8192]        (32 KB)
#define WS_CNT 1351680         // int counts[2048]             (8 KB)
#define WS_FLAGCNT 1359872     // int flag_count               (pad to 1 KB)
#define WS_FLAGGED 1360896     // int flagged[65536]           (256 KB)

// ---------------------------------------------------------------------------
// 64x64 tile transpose (R x C row-major in  ->  C x R row-major out)
// ---------------------------------------------------------------------------
__global__ __launch_bounds__(256) void transpose64(const float* __restrict__ in,
                                                   float* __restrict__ out,
                                                   int R, int C) {
  __shared__ float tile[64][65];
  const int tid = threadIdx.x;
  const int r0 = blockIdx.x * 64;
  const int c0 = blockIdx.y * 64;
#pragma unroll
  for (int it = 0; it < 4; ++it) {
    int idx = tid + it * 256;
    int row = idx >> 4;
    int c4 = (idx & 15) * 4;
    float4 v = *(const float4*)(in + (size_t)(r0 + row) * C + c0 + c4);
    tile[row][c4 + 0] = v.x;
    tile[row][c4 + 1] = v.y;
    tile[row][c4 + 2] = v.z;
    tile[row][c4 + 3] = v.w;
  }
  __syncthreads();
#pragma unroll
  for (int it = 0; it < 4; ++it) {
    int idx = tid + it * 256;
    int row = idx >> 4;      // output-row-local (input col)
    int c4 = (idx & 15) * 4; // along R
    float4 v;
    v.x = tile[c4 + 0][row];
    v.y = tile[c4 + 1][row];
    v.z = tile[c4 + 2][row];
    v.w = tile[c4 + 3][row];
    *(float4*)(out + (size_t)(c0 + row) * R + r0 + c4) = v;
  }
}

// ---------------------------------------------------------------------------
// Emulated-np ||k||^2: terms rounded to fp32 (w*w), summed in fp64 (within
// ~1 ulp of any np pairwise order), rounded back to fp32.
// ---------------------------------------------------------------------------
__global__ __launch_bounds__(256) void l2_kernel(const float* __restrict__ w,
                                                 float* __restrict__ l2k) {
  int i = blockIdx.x * 256 + threadIdx.x;  // code id, grid covers 2048
  const float4* p = (const float4*)(w + (size_t)i * D_DIM);
  double s = 0.0;
#pragma unroll
  for (int j = 0; j < 32; ++j) {
    float4 v = p[j];
    float t0 = v.x * v.x;  // fp32 rounding of each term, like np's w*w
    float t1 = v.y * v.y;
    float t2 = v.z * v.z;
    float t3 = v.w * v.w;
    s += (double)t0;
    s += (double)t1;
    s += (double)t2;
    s += (double)t3;
  }
  l2k[i] = (float)s;
}

// ---------------------------------------------------------------------------
// Pass 1: fp32 argmin over codes with dist = l2k - 2*q.k (l2_q dropped —
// ordering-equivalent). Tracks best + second-best; queries with gap < MARGIN
// are flagged for exact re-resolution emulating the reference's fp32 math.
// ---------------------------------------------------------------------------
__global__ __launch_bounds__(256) void argmin_kernel(const float* __restrict__ x,
                                                     const float* __restrict__ wT,
                                                     const float* __restrict__ l2k,
                                                     int* __restrict__ best_idx,
                                                     int* __restrict__ flag_count,
                                                     int* __restrict__ flagged) {
  __shared__ float qT[D_DIM * 64];
  __shared__ float kT[D_DIM * 64];
  const int tid = threadIdx.x;
  const int q0 = blockIdx.x * 64;

  // Stage q tile transposed: qT[d*64 + qi] = x[q0+qi][d].
  {
    int row = tid & 63;
    int c4b = tid >> 6;  // 0..3
    const float* xb = x + (size_t)(q0 + row) * D_DIM;
#pragma unroll
    for (int it = 0; it < 8; ++it) {
      int c4 = c4b + it * 4;  // 0..31
      float4 v = *(const float4*)(xb + c4 * 4);
      int d = c4 * 4;
      qT[(d + 0) * 64 + row] = v.x;
      qT[(d + 1) * 64 + row] = v.y;
      qT[(d + 2) * 64 + row] = v.z;
      qT[(d + 3) * 64 + row] = v.w;
    }
  }

  const int qr = (tid & 15) * 4;  // 4 consecutive queries
  const int kr = (tid >> 4) * 4;  // 4 consecutive codes (within chunk)
  float bestD[4] = {3.4e38f, 3.4e38f, 3.4e38f, 3.4e38f};
  float secD[4] = {3.4e38f, 3.4e38f, 3.4e38f, 3.4e38f};
  int bestI[4] = {0, 0, 0, 0};

  for (int ch = 0; ch < M_CODES / 64; ++ch) {
    __syncthreads();  // protect kT (and initial qT writes) from readers
    {
#pragma unroll
      for (int it = 0; it < 8; ++it) {
        int idx = tid + it * 256;      // float4 id in [0,2048)
        int d = idx >> 4;              // 0..127
        int c4 = (idx & 15) * 4;       // 0..60
        float4 v = *(const float4*)(wT + (size_t)d * M_CODES + ch * 64 + c4);
        *(float4*)(kT + d * 64 + c4) = v;
      }
    }
    __syncthreads();

    float acc[4][4];
#pragma unroll
    for (int i = 0; i < 4; ++i)
#pragma unroll
      for (int j = 0; j < 4; ++j) acc[i][j] = 0.f;

#pragma unroll 8
    for (int d = 0; d < D_DIM; ++d) {
      float4 qv = *(const float4*)&qT[d * 64 + qr];
      float4 kv = *(const float4*)&kT[d * 64 + kr];
      acc[0][0] = fmaf(qv.x, kv.x, acc[0][0]);
      acc[0][1] = fmaf(qv.x, kv.y, acc[0][1]);
      acc[0][2] = fmaf(qv.x, kv.z, acc[0][2]);
      acc[0][3] = fmaf(qv.x, kv.w, acc[0][3]);
      acc[1][0] = fmaf(qv.y, kv.x, acc[1][0]);
      acc[1][1] = fmaf(qv.y, kv.y, acc[1][1]);
      acc[1][2] = fmaf(qv.y, kv.z, acc[1][2]);
      acc[1][3] = fmaf(qv.y, kv.w, acc[1][3]);
      acc[2][0] = fmaf(qv.z, kv.x, acc[2][0]);
      acc[2][1] = fmaf(qv.z, kv.y, acc[2][1]);
      acc[2][2] = fmaf(qv.z, kv.z, acc[2][2]);
      acc[2][3] = fmaf(qv.z, kv.w, acc[2][3]);
      acc[3][0] = fmaf(qv.w, kv.x, acc[3][0]);
      acc[3][1] = fmaf(qv.w, kv.y, acc[3][1]);
      acc[3][2] = fmaf(qv.w, kv.z, acc[3][2]);
      acc[3][3] = fmaf(qv.w, kv.w, acc[3][3]);
    }

    int cbase = ch * 64 + kr;
#pragma unroll
    for (int j = 0; j < 4; ++j) {
      float l2 = l2k[cbase + j];
#pragma unroll
      for (int i = 0; i < 4; ++i) {
        float dd = fmaf(-2.0f, acc[i][j], l2);
        if (dd < bestD[i]) {
          secD[i] = bestD[i];
          bestD[i] = dd;
          bestI[i] = cbase + j;
        } else if (dd < secD[i]) {
          secD[i] = dd;
        }
      }
    }
  }

  // Cross-thread reduction: 16 code-groups per query, merge (best, second).
  __syncthreads();
  float* redD = qT;                 // 64*16 floats
  int* redI = (int*)(qT + 1024);    // 64*16 ints
  float* redS = qT + 2048;          // 64*16 floats
  int g = tid >> 4;
#pragma unroll
  for (int i = 0; i < 4; ++i) {
    redD[(qr + i) * 16 + g] = bestD[i];
    redI[(qr + i) * 16 + g] = bestI[i];
    redS[(qr + i) * 16 + g] = secD[i];
  }
  __syncthreads();
  if (tid < 64) {
    float bd = redD[tid * 16];
    int bi = redI[tid * 16];
    float sd = redS[tid * 16];
#pragma unroll
    for (int g2 = 1; g2 < 16; ++g2) {
      float dg = redD[tid * 16 + g2];
      int ig = redI[tid * 16 + g2];
      float sg = redS[tid * 16 + g2];
      if (dg < bd) {
        sd = fminf(bd, sg);
        bd = dg;
        bi = ig;
      } else {
        if (dg == bd && ig < bi) bi = ig;
        sd = fminf(sd, dg);  // dg >= bd; sg >= dg so dg suffices
      }
    }
    best_idx[q0 + tid] = bi;
    if (sd - bd < MARGIN) {  // near-tie: resolve by emulating reference fp32
      int pos = atomicAdd(flag_count, 1);
      flagged[pos] = q0 + tid;
    }
  }
}

// ---------------------------------------------------------------------------
// Fixup: for flagged queries, emulate the reference's fp32 computation:
//   dist = fl32( fl32(l2q32 + l2k32[c]) - fl32(2 * fl32(q.k)) )
// with l2q32/l2k32 = fp32-rounded fp64 sums of fp32-squared terms and
// q.k computed exactly in fp64 then rounded once to fp32 (within ~1-2 ulp
// of any BLAS accumulation order). First-index tie-break == np.argmin.
// ---------------------------------------------------------------------------
__global__ __launch_bounds__(256) void fixup_kernel(const float* __restrict__ x,
                                                    const float* __restrict__ w,
                                                    const float* __restrict__ l2k32,
                                                    const int* __restrict__ flagged,
                                                    const int* __restrict__ flag_count,
                                                    int* __restrict__ best_idx) {
  __shared__ float qs[D_DIM];
  __shared__ float l2q_sh;
  __shared__ float redD[256];
  __shared__ int redI[256];
  const int tid = threadIdx.x;
  const int n = *flag_count;
  for (int f = blockIdx.x; f < n; f += gridDim.x) {
    __syncthreads();  // protect qs/red from previous iteration readers
    int q = flagged[f];
    if (tid < D_DIM) qs[tid] = x[(size_t)q * D_DIM + tid];
    __syncthreads();
    if (tid == 0) {
      double s = 0.0;
      for (int d = 0; d < D_DIM; ++d) {
        float t = qs[d] * qs[d];  // fp32 term rounding, like np's x*x
        s += (double)t;
      }
      l2q_sh = (float)s;
    }
    __syncthreads();
    const float l2q = l2q_sh;
    float bd = 3.4e38f;
    int bi = 0x7fffffff;
    for (int c = tid; c < M_CODES; c += 256) {  // ascending per thread
      const float4* wr = (const float4*)(w + (size_t)c * D_DIM);
      double s = 0.0;
#pragma unroll
      for (int j = 0; j < 32; ++j) {
        float4 v = wr[j];
        s = fma((double)qs[j * 4 + 0], (double)v.x, s);
        s = fma((double)qs[j * 4 + 1], (double)v.y, s);
        s = fma((double)qs[j * 4 + 2], (double)v.z, s);
        s = fma((double)qs[j * 4 + 3], (double)v.w, s);
      }
      float simf = (float)s;            // one fp32 rounding of the dot
      float S = l2q + l2k32[c];         // fp32 add (l2_q + l2_k)
      float T = 2.0f * simf;            // exact power-of-2 scale
      float dist = S - T;               // fp32 subtract
      if (dist < bd) { bd = dist; bi = c; }  // strict <: first index wins
    }
    redD[tid] = bd;
    redI[tid] = bi;
    __syncthreads();
    for (int off = 128; off; off >>= 1) {
      if (tid < off) {
        float od = redD[tid + off];
        int oi = redI[tid + off];
        if (od < redD[tid] || (od == redD[tid] && oi < redI[tid])) {
          redD[tid] = od;
          redI[tid] = oi;
        }
      }
      __syncthreads();
    }
    if (tid == 0) best_idx[q] = redI[0];
  }
}

// ---------------------------------------------------------------------------
// Gather + straight-through output + loss partials + histogram + indices out
// ---------------------------------------------------------------------------
__global__ __launch_bounds__(256) void epilogue_kernel(const float* __restrict__ x,
                                                       const float* __restrict__ w,
                                                       const int* __restrict__ best_idx,
                                                       float* __restrict__ out,
                                                       float* __restrict__ part,
                                                       int* __restrict__ counts) {
  int gid = blockIdx.x * 256 + threadIdx.x;  // float4 id, 2,097,152 total
  int q = gid >> 5;
  int d4 = gid & 31;
  int idx = best_idx[q];
  float4 xv = ((const float4*)x)[gid];
  float4 wv = ((const float4*)w)[(size_t)idx * 32 + d4];
  float4 o;
  float t0 = wv.x - xv.x; o.x = xv.x + t0; float e0 = o.x - xv.x;
  float t1 = wv.y - xv.y; o.y = xv.y + t1; float e1 = o.y - xv.y;
  float t2 = wv.z - xv.z; o.z = xv.z + t2; float e2 = o.z - xv.z;
  float t3 = wv.w - xv.w; o.w = xv.w + t3; float e3 = o.w - xv.w;
  float ls = e0 * e0 + e1 * e1 + e2 * e2 + e3 * e3;
  ((float4*)out)[gid] = o;

  for (int off = 32; off; off >>= 1) ls += __shfl_down(ls, off);
  __shared__ float red[4];
  if ((threadIdx.x & 63) == 0) red[threadIdx.x >> 6] = ls;
  __syncthreads();
  if (threadIdx.x == 0) part[blockIdx.x] = red[0] + red[1] + red[2] + red[3];

  if (d4 == 0) {
    out[OUT_IDX + q] = (float)idx;  // harness reads tuple as fp32
    atomicAdd(&counts[idx], 1);
  }
}

// ---------------------------------------------------------------------------
// Finalize: loss mean + perplexity
// ---------------------------------------------------------------------------
__global__ __launch_bounds__(256) void finalize_kernel(const int* __restrict__ counts,
                                                       const float* __restrict__ part,
                                                       float* __restrict__ out) {
  int tid = threadIdx.x;
  float ls = 0.f;
  for (int i = tid; i < 8192; i += 256) ls += part[i];
  float es = 0.f;
  for (int i = tid; i < M_CODES; i += 256) {
    float p = (float)counts[i] * (1.0f / 65536.0f);
    es += p * logf(p + 1e-10f);
  }
  for (int off = 32; off; off >>= 1) {
    ls += __shfl_down(ls, off);
    es += __shfl_down(es, off);
  }
  __shared__ float redl[4], rede[4];
  if ((tid & 63) == 0) {
    redl[tid >> 6] = ls;
    rede[tid >> 6] = es;
  }
  __syncthreads();
  if (tid == 0) {
    out[OUT_LOSS] = (redl[0] + redl[1] + redl[2] + redl[3]) * (1.0f / 8388608.0f);
    out[OUT_PERP] = expf(-(rede[0] + rede[1] + rede[2] + rede[3]));
  }
}

extern "C" void kernel_launch(void* const* d_in, const int* in_sizes, int n_in,
                              void* d_out, int out_size, void* d_ws, size_t ws_size,
                              hipStream_t stream) {
  const float* x = (const float*)d_in[0];
  const float* w = (const float*)d_in[1];
  float* out = (float*)d_out;
  char* ws = (char*)d_ws;
  float* wT = (float*)(ws + WS_WT);
  float* l2k = (float*)(ws + WS_L2K);
  int* bidx = (int*)(ws + WS_IDX);
  float* part = (float*)(ws + WS_PART);
  int* counts = (int*)(ws + WS_CNT);
  int* flagcnt = (int*)(ws + WS_FLAGCNT);
  int* flagged = (int*)(ws + WS_FLAGGED);

  hipMemsetAsync(counts, 0, M_CODES * sizeof(int), stream);
  hipMemsetAsync(flagcnt, 0, sizeof(int), stream);
  transpose64<<<dim3(32, 2), 256, 0, stream>>>(w, wT, M_CODES, D_DIM);
  l2_kernel<<<8, 256, 0, stream>>>(w, l2k);
  argmin_kernel<<<1024, 256, 0, stream>>>(x, wT, l2k, bidx, flagcnt, flagged);
  fixup_kernel<<<256, 256, 0, stream>>>(x, w, l2k, flagged, flagcnt, bidx);
  epilogue_kernel<<<8192, 256, 0, stream>>>(x, w, bidx, out, part, counts);
  finalize_kernel<<<1, 256, 0, stream>>>(counts, part, out);
}

// Round 4
// 428.281 us; speedup vs baseline: 1.4873x; 1.4873x over previous
//
#include <hip/hip_runtime.h>
#include <hip/hip_bf16.h>
#include <math.h>

// Problem constants
#define D_DIM 128
#define M_CODES 2048
#define BN_TOT 65536           // B*N = 16*4096
#define OUT_LOSS 8388608       // flat offset of loss
#define OUT_PERP 8388609       // flat offset of perp
#define OUT_IDX 8388610        // flat offset of indices
#define MARGIN 2e-3f           // covers ref fp32 noise (~1.6e-5) + bf16-split err (~2e-4)

// ws byte offsets
#define WS_L2K 0               // float l2k[2048]              (8 KB)
#define WS_IDX 8192            // int best_idx[65536]          (256 KB)
#define WS_PART 270336         // float loss_part[8192]        (32 KB)
#define WS_CNT 303104          // int counts[2048]             (8 KB)
#define WS_FLAGCNT 311296      // int flag_count               (pad to 1 KB)
#define WS_FLAGGED 312320      // int flagged[65536]           (256 KB)

typedef __bf16 bf16x8 __attribute__((ext_vector_type(8)));
typedef float f32x4 __attribute__((ext_vector_type(4)));

#define A_STRIDE 136           // bf16 units; 16B-aligned fragment reads

// ---------------------------------------------------------------------------
// Emulated-np ||k||^2: terms rounded to fp32 (w*w), summed in fp64, rounded
// back to fp32 (matches the reference's fp32 sum within ~1 ulp).
// ---------------------------------------------------------------------------
__global__ __launch_bounds__(256) void l2_kernel(const float* __restrict__ w,
                                                 float* __restrict__ l2k) {
  int i = blockIdx.x * 256 + threadIdx.x;
  const float4* p = (const float4*)(w + (size_t)i * D_DIM);
  double s = 0.0;
#pragma unroll
  for (int j = 0; j < 32; ++j) {
    float4 v = p[j];
    s += (double)(v.x * v.x);
    s += (double)(v.y * v.y);
    s += (double)(v.z * v.z);
    s += (double)(v.w * v.w);
  }
  l2k[i] = (float)s;
}

// merge (ob,os,oi) into (b,s,i): best+second-best with first-index tie-break
__device__ __forceinline__ void merge_bs(float& b, float& s, int& i,
                                         float ob, float os, int oi) {
  if (ob < b) {
    s = fminf(b, os);
    b = ob;
    i = oi;
  } else if (ob > b) {
    s = fminf(s, ob);
  } else {           // tie: second-best == best (gap 0 -> will be flagged)
    s = b;
    if (oi < i) i = oi;
  }
}

// ---------------------------------------------------------------------------
// MFMA argmin: dist = l2k - 2*q.k via split-bf16 (hi/lo) 16x16x32 MFMA.
// Block = 512 threads (8 waves) handles 64 queries x ALL 2048 codes.
// A (queries, hi/lo bf16) staged once in LDS; each wave holds one 64-code
// chunk's B-fragments in registers, looping over 4 chunks. No barriers in
// the compute loop. Near-ties (gap < MARGIN) flagged for exact fixup.
// ---------------------------------------------------------------------------
__global__ __launch_bounds__(512, 2) void argmin_mfma(
    const float* __restrict__ x, const float* __restrict__ w,
    const float* __restrict__ l2k, int* __restrict__ best_idx,
    int* __restrict__ flag_count, int* __restrict__ flagged) {
  __shared__ __bf16 aHi[64 * A_STRIDE];
  __shared__ __bf16 aLo[64 * A_STRIDE];
  __shared__ float redB[32][64];
  __shared__ float redS[32][64];
  __shared__ int redI[32][64];

  const int tid = threadIdx.x;
  const int q0 = blockIdx.x * 64;
  const int wv = tid >> 6;        // wave 0..7
  const int lane = tid & 63;
  const int col = lane & 15;      // MFMA n-index / A m-index
  const int quad = lane >> 4;     // 0..3

  // ---- Stage A tile (64q x 128k), converting fp32 -> hi/lo bf16 ----
#pragma unroll
  for (int it = 0; it < 4; ++it) {
    int fid = tid + it * 512;           // float4 id in [0, 2048)
    int q = fid >> 5;
    int k4 = (fid & 31) * 4;
    float4 v = *(const float4*)(x + (size_t)(q0 + q) * D_DIM + k4);
    float f[4] = {v.x, v.y, v.z, v.w};
    int base = q * A_STRIDE + k4;
#pragma unroll
    for (int j = 0; j < 4; ++j) {
      __bf16 h = (__bf16)f[j];
      aHi[base + j] = h;
      aLo[base + j] = (__bf16)(f[j] - (float)h);
    }
  }
  __syncthreads();

  // ---- Per-wave chunk loop: 64 codes resident in registers ----
  for (int ch = 0; ch < 4; ++ch) {
    const int cb = ch * 512 + wv * 64;  // this wave-chunk's first code

    // Load B fragments from global w (L2-hot), convert to hi/lo bf16.
    bf16x8 bhi[4][4], blo[4][4];        // [nt][ks] -> 128 VGPR total
#pragma unroll
    for (int nt = 0; nt < 4; ++nt) {
#pragma unroll
      for (int ks = 0; ks < 4; ++ks) {
        const float* wp = w + (size_t)(cb + 16 * nt + col) * D_DIM + 32 * ks + quad * 8;
        float4 u = *(const float4*)wp;
        float4 v = *(const float4*)(wp + 4);
        float f[8] = {u.x, u.y, u.z, u.w, v.x, v.y, v.z, v.w};
#pragma unroll
        for (int j = 0; j < 8; ++j) {
          __bf16 h = (__bf16)f[j];
          bhi[nt][ks][j] = h;
          blo[nt][ks][j] = (__bf16)(f[j] - (float)h);
        }
      }
    }
    float l2c[4];
#pragma unroll
    for (int nt = 0; nt < 4; ++nt) l2c[nt] = l2k[cb + 16 * nt + col];

    f32x4 acc[4][4];                    // [mt][nt]
#pragma unroll
    for (int mt = 0; mt < 4; ++mt)
#pragma unroll
      for (int nt = 0; nt < 4; ++nt) acc[mt][nt] = (f32x4){0.f, 0.f, 0.f, 0.f};

    // ---- MFMA K-loop: q.k = ahi*bhi + ahi*blo + alo*bhi ----
#pragma unroll
    for (int ks = 0; ks < 4; ++ks) {
      bf16x8 ah[4], al[4];
#pragma unroll
      for (int mt = 0; mt < 4; ++mt) {
        int off = (16 * mt + col) * A_STRIDE + 32 * ks + quad * 8;
        ah[mt] = *(const bf16x8*)&aHi[off];
        al[mt] = *(const bf16x8*)&aLo[off];
      }
#pragma unroll
      for (int nt = 0; nt < 4; ++nt) {
#pragma unroll
        for (int mt = 0; mt < 4; ++mt) {
          acc[mt][nt] = __builtin_amdgcn_mfma_f32_16x16x32_bf16(
              al[mt], bhi[nt][ks], acc[mt][nt], 0, 0, 0);
          acc[mt][nt] = __builtin_amdgcn_mfma_f32_16x16x32_bf16(
              ah[mt], blo[nt][ks], acc[mt][nt], 0, 0, 0);
          acc[mt][nt] = __builtin_amdgcn_mfma_f32_16x16x32_bf16(
              ah[mt], bhi[nt][ks], acc[mt][nt], 0, 0, 0);
        }
      }
    }

    // ---- dist + per-chunk argmin; reduce across the 16 lanes of each quad.
    // C/D layout: element r of lane: query = q0+16*mt+quad*4+r, code = cb+16*nt+col.
    const int slot = wv * 4 + ch;
#pragma unroll
    for (int mt = 0; mt < 4; ++mt) {
#pragma unroll
      for (int r = 0; r < 4; ++r) {
        float bd = 3.4e38f, sd = 3.4e38f;
        int bi = 0;
#pragma unroll
        for (int nt = 0; nt < 4; ++nt) {
          float dd = fmaf(-2.0f, acc[mt][nt][r], l2c[nt]);
          int ci = cb + 16 * nt + col;
          if (dd < bd) { sd = bd; bd = dd; bi = ci; }
          else if (dd > bd) { sd = fminf(sd, dd); }
          else { sd = bd; if (ci < bi) bi = ci; }
        }
#pragma unroll
        for (int m = 1; m < 16; m <<= 1) {
          float ob = __shfl_xor(bd, m);
          float os = __shfl_xor(sd, m);
          int oi = __shfl_xor(bi, m);
          merge_bs(bd, sd, bi, ob, os, oi);
        }
        if (col == mt * 4 + r) {        // one writer per (mt,r) per quad
          int qloc = 16 * mt + 4 * quad + r;
          redB[slot][qloc] = bd;
          redS[slot][qloc] = sd;
          redI[slot][qloc] = bi;
        }
      }
    }
  }

  __syncthreads();

  // ---- Final merge: 32 slots per query, ascending code order (ch, wv) ----
  if (tid < 64) {
    float bd = 3.4e38f, sd = 3.4e38f;
    int bi = 0x7fffffff;
#pragma unroll
    for (int ch = 0; ch < 4; ++ch) {
#pragma unroll
      for (int w8 = 0; w8 < 8; ++w8) {
        int slot = w8 * 4 + ch;
        merge_bs(bd, sd, bi, redB[slot][tid], redS[slot][tid], redI[slot][tid]);
      }
    }
    best_idx[q0 + tid] = bi;
    if (sd - bd < MARGIN) {
      int pos = atomicAdd(flag_count, 1);
      flagged[pos] = q0 + tid;
    }
  }
}

// ---------------------------------------------------------------------------
// Fixup: for flagged queries, emulate the reference's fp32 computation:
//   dist = fl32( fl32(l2q32 + l2k32[c]) - fl32(2 * fl32(q.k)) )
// q.k exact in fp64 then rounded once to fp32. First-index tie-break.
// ---------------------------------------------------------------------------
__global__ __launch_bounds__(256) void fixup_kernel(const float* __restrict__ x,
                                                    const float* __restrict__ w,
                                                    const float* __restrict__ l2k32,
                                                    const int* __restrict__ flagged,
                                                    const int* __restrict__ flag_count,
                                                    int* __restrict__ best_idx) {
  __shared__ float qs[D_DIM];
  __shared__ float l2q_sh;
  __shared__ float redD[256];
  __shared__ int redI[256];
  const int tid = threadIdx.x;
  const int n = *flag_count;
  for (int f = blockIdx.x; f < n; f += gridDim.x) {
    __syncthreads();
    int q = flagged[f];
    if (tid < D_DIM) qs[tid] = x[(size_t)q * D_DIM + tid];
    __syncthreads();
    if (tid == 0) {
      double s = 0.0;
      for (int d = 0; d < D_DIM; ++d) {
        float t = qs[d] * qs[d];
        s += (double)t;
      }
      l2q_sh = (float)s;
    }
    __syncthreads();
    const float l2q = l2q_sh;
    float bd = 3.4e38f;
    int bi = 0x7fffffff;
    for (int c = tid; c < M_CODES; c += 256) {
      const float4* wr = (const float4*)(w + (size_t)c * D_DIM);
      double s = 0.0;
#pragma unroll
      for (int j = 0; j < 32; ++j) {
        float4 v = wr[j];
        s = fma((double)qs[j * 4 + 0], (double)v.x, s);
        s = fma((double)qs[j * 4 + 1], (double)v.y, s);
        s = fma((double)qs[j * 4 + 2], (double)v.z, s);
        s = fma((double)qs[j * 4 + 3], (double)v.w, s);
      }
      float simf = (float)s;
      float S = l2q + l2k32[c];
      float T = 2.0f * simf;
      float dist = S - T;
      if (dist < bd) { bd = dist; bi = c; }
    }
    redD[tid] = bd;
    redI[tid] = bi;
    __syncthreads();
    for (int off = 128; off; off >>= 1) {
      if (tid < off) {
        float od = redD[tid + off];
        int oi = redI[tid + off];
        if (od < redD[tid] || (od == redD[tid] && oi < redI[tid])) {
          redD[tid] = od;
          redI[tid] = oi;
        }
      }
      __syncthreads();
    }
    if (tid == 0) best_idx[q] = redI[0];
  }
}

// ---------------------------------------------------------------------------
// Gather + straight-through output + loss partials + histogram + indices out
// ---------------------------------------------------------------------------
__global__ __launch_bounds__(256) void epilogue_kernel(const float* __restrict__ x,
                                                       const float* __restrict__ w,
                                                       const int* __restrict__ best_idx,
                                                       float* __restrict__ out,
                                                       float* __restrict__ part,
                                                       int* __restrict__ counts) {
  int gid = blockIdx.x * 256 + threadIdx.x;  // float4 id, 2,097,152 total
  int q = gid >> 5;
  int d4 = gid & 31;
  int idx = best_idx[q];
  float4 xv = ((const float4*)x)[gid];
  float4 wv = ((const float4*)w)[(size_t)idx * 32 + d4];
  float4 o;
  float t0 = wv.x - xv.x; o.x = xv.x + t0; float e0 = o.x - xv.x;
  float t1 = wv.y - xv.y; o.y = xv.y + t1; float e1 = o.y - xv.y;
  float t2 = wv.z - xv.z; o.z = xv.z + t2; float e2 = o.z - xv.z;
  float t3 = wv.w - xv.w; o.w = xv.w + t3; float e3 = o.w - xv.w;
  float ls = e0 * e0 + e1 * e1 + e2 * e2 + e3 * e3;
  ((float4*)out)[gid] = o;

  for (int off = 32; off; off >>= 1) ls += __shfl_down(ls, off);
  __shared__ float red[4];
  if ((threadIdx.x & 63) == 0) red[threadIdx.x >> 6] = ls;
  __syncthreads();
  if (threadIdx.x == 0) part[blockIdx.x] = red[0] + red[1] + red[2] + red[3];

  if (d4 == 0) {
    out[OUT_IDX + q] = (float)idx;
    atomicAdd(&counts[idx], 1);
  }
}

// ---------------------------------------------------------------------------
// Finalize: loss mean + perplexity
// ---------------------------------------------------------------------------
__global__ __launch_bounds__(256) void finalize_kernel(const int* __restrict__ counts,
                                                       const float* __restrict__ part,
                                                       float* __restrict__ out) {
  int tid = threadIdx.x;
  float ls = 0.f;
  for (int i = tid; i < 8192; i += 256) ls += part[i];
  float es = 0.f;
  for (int i = tid; i < M_CODES; i += 256) {
    float p = (float)counts[i] * (1.0f / 65536.0f);
    es += p * logf(p + 1e-10f);
  }
  for (int off = 32; off; off >>= 1) {
    ls += __shfl_down(ls, off);
    es += __shfl_down(es, off);
  }
  __shared__ float redl[4], rede[4];
  if ((tid & 63) == 0) {
    redl[tid >> 6] = ls;
    rede[tid >> 6] = es;
  }
  __syncthreads();
  if (tid == 0) {
    out[OUT_LOSS] = (redl[0] + redl[1] + redl[2] + redl[3]) * (1.0f / 8388608.0f);
    out[OUT_PERP] = expf(-(rede[0] + rede[1] + rede[2] + rede[3]));
  }
}

extern "C" void kernel_launch(void* const* d_in, const int* in_sizes, int n_in,
                              void* d_out, int out_size, void* d_ws, size_t ws_size,
                              hipStream_t stream) {
  const float* x = (const float*)d_in[0];
  const float* w = (const float*)d_in[1];
  float* out = (float*)d_out;
  char* ws = (char*)d_ws;
  float* l2k = (float*)(ws + WS_L2K);
  int* bidx = (int*)(ws + WS_IDX);
  float* part = (float*)(ws + WS_PART);
  int* counts = (int*)(ws + WS_CNT);
  int* flagcnt = (int*)(ws + WS_FLAGCNT);
  int* flagged = (int*)(ws + WS_FLAGGED);

  hipMemsetAsync(counts, 0, M_CODES * sizeof(int), stream);
  hipMemsetAsync(flagcnt, 0, sizeof(int), stream);
  l2_kernel<<<8, 256, 0, stream>>>(w, l2k);
  argmin_mfma<<<1024, 512, 0, stream>>>(x, w, l2k, bidx, flagcnt, flagged);
  fixup_kernel<<<256, 256, 0, stream>>>(x, w, l2k, flagged, flagcnt, bidx);
  epilogue_kernel<<<8192, 256, 0, stream>>>(x, w, bidx, out, part, counts);
  finalize_kernel<<<1, 256, 0, stream>>>(counts, part, out);
}